// Round 1
// baseline (165.789 us; speedup 1.0000x reference)
//
#include <hip/hip_runtime.h>

#define N_NEURONS 1024
#define TABLE_SIZE 65536
#define BATCH 8192

// One wave (64 lanes) per sample. Lane l handles neurons {256k + 4l .. +3},
// k = 0..3  -> 16 neurons/lane, 64*16 = 1024 neurons total.
// Index loads: int4 per lane, 64 lanes * 16 B = 1 KiB contiguous per pass.
// Gathers: 16 independent random table reads per lane (MLP for latency hiding).
__global__ __launch_bounds__(256) void qw_gather_kernel(
    const int* __restrict__ data,
    const float* __restrict__ table,
    float* __restrict__ out)
{
    const int gtid    = blockIdx.x * blockDim.x + threadIdx.x;
    const int sample  = gtid >> 6;          // one wave per sample
    const int lane    = threadIdx.x & 63;
    if (sample >= BATCH) return;

    const int* __restrict__ row = data + (size_t)sample * N_NEURONS;

    float acc = 0.0f;
#pragma unroll
    for (int k = 0; k < 4; ++k) {
        const int jb = 256 * k + 4 * lane;
        const int4 idx4 = *reinterpret_cast<const int4*>(row + jb);
        // 4 independent gathers; rows jb..jb+3 of the table
        acc += table[(size_t)(jb + 0) * TABLE_SIZE + idx4.x];
        acc += table[(size_t)(jb + 1) * TABLE_SIZE + idx4.y];
        acc += table[(size_t)(jb + 2) * TABLE_SIZE + idx4.z];
        acc += table[(size_t)(jb + 3) * TABLE_SIZE + idx4.w];
    }

    // full-wave (64-lane) butterfly reduction
#pragma unroll
    for (int off = 32; off >= 1; off >>= 1) {
        acc += __shfl_xor(acc, off, 64);
    }

    if (lane == 0) {
        out[sample] = acc;
    }
}

extern "C" void kernel_launch(void* const* d_in, const int* in_sizes, int n_in,
                              void* d_out, int out_size, void* d_ws, size_t ws_size,
                              hipStream_t stream)
{
    const int*   data  = (const int*)d_in[0];    // [BATCH, N_NEURONS] int32
    const float* table = (const float*)d_in[1];  // [N_NEURONS, TABLE_SIZE] float32
    float*       out   = (float*)d_out;          // [BATCH] float32

    // 1 wave per sample, 4 waves per 256-thread block
    const int blocks = BATCH / 4;  // 2048
    qw_gather_kernel<<<blocks, 256, 0, stream>>>(data, table, out);
}

// Round 2
// 91.784 us; speedup vs baseline: 1.8063x; 1.8063x over previous
//
#include <hip/hip_runtime.h>

#define N_NEURONS 1024
#define TABLE_SIZE 65536
#define BATCH 8192
#define NGROUPS 8            // one neuron-group per XCD
#define NPG 128              // neurons per group
#define HALF 64              // neurons per thread (2 threads per sample)
#define SPB 128              // samples per block

// Pass 1: neuron-major partial sums with XCD-affine grouping.
// Block b: group g = b%8 (lands on XCD g via round-robin dispatch),
//          samples [ (b>>3)*128, +128 ).
// Thread t: sample (t&127), neuron range [g*128 + (t>>7)*64, +64).
// All gathers into a given table row happen within one XCD's 64 blocks in a
// short window -> row working set (~227 KB) stays L2-resident.
__global__ __launch_bounds__(256) void qw_partial_kernel(
    const int* __restrict__ data,
    const float* __restrict__ table,
    float* __restrict__ part)           // [NGROUPS][BATCH]
{
    const int b      = blockIdx.x;
    const int g      = b & (NGROUPS - 1);
    const int sub    = b >> 3;
    const int t      = threadIdx.x;
    const int half   = t >> 7;                       // 0 or 1
    const int sid    = t & (SPB - 1);
    const int sample = sub * SPB + sid;
    const int jbase  = g * NPG + half * HALF;

    const int* __restrict__ drow = data + (size_t)sample * N_NEURONS + jbase;

    float acc = 0.0f;
#pragma unroll
    for (int jo = 0; jo < HALF; jo += 16) {
        // 4 coalesced-per-thread int4 index loads (16-B aligned)
        const int4 i0 = *reinterpret_cast<const int4*>(drow + jo);
        const int4 i1 = *reinterpret_cast<const int4*>(drow + jo + 4);
        const int4 i2 = *reinterpret_cast<const int4*>(drow + jo + 8);
        const int4 i3 = *reinterpret_cast<const int4*>(drow + jo + 12);
        const float* __restrict__ tp = table + (size_t)(jbase + jo) * TABLE_SIZE;
        // 16 independent gathers in flight per lane
        const float v0  = tp[(size_t) 0 * TABLE_SIZE + i0.x];
        const float v1  = tp[(size_t) 1 * TABLE_SIZE + i0.y];
        const float v2  = tp[(size_t) 2 * TABLE_SIZE + i0.z];
        const float v3  = tp[(size_t) 3 * TABLE_SIZE + i0.w];
        const float v4  = tp[(size_t) 4 * TABLE_SIZE + i1.x];
        const float v5  = tp[(size_t) 5 * TABLE_SIZE + i1.y];
        const float v6  = tp[(size_t) 6 * TABLE_SIZE + i1.z];
        const float v7  = tp[(size_t) 7 * TABLE_SIZE + i1.w];
        const float v8  = tp[(size_t) 8 * TABLE_SIZE + i2.x];
        const float v9  = tp[(size_t) 9 * TABLE_SIZE + i2.y];
        const float v10 = tp[(size_t)10 * TABLE_SIZE + i2.z];
        const float v11 = tp[(size_t)11 * TABLE_SIZE + i2.w];
        const float v12 = tp[(size_t)12 * TABLE_SIZE + i3.x];
        const float v13 = tp[(size_t)13 * TABLE_SIZE + i3.y];
        const float v14 = tp[(size_t)14 * TABLE_SIZE + i3.z];
        const float v15 = tp[(size_t)15 * TABLE_SIZE + i3.w];
        acc += (((v0 + v1) + (v2 + v3)) + ((v4 + v5) + (v6 + v7)))
             + (((v8 + v9) + (v10 + v11)) + ((v12 + v13) + (v14 + v15)));
    }

    // combine the two halves of each sample via LDS
    __shared__ float lds[SPB];
    if (half == 0) {
        lds[sid] = acc;
    }
    __syncthreads();
    if (half == 1) {
        part[(size_t)g * BATCH + sample] = lds[sid] + acc;  // coalesced
    }
}

// Pass 2: out[i] = sum_g part[g][i]
__global__ __launch_bounds__(256) void qw_reduce_kernel(
    const float* __restrict__ part,
    float* __restrict__ out)
{
    const int i = blockIdx.x * 256 + threadIdx.x;
    float s = 0.0f;
#pragma unroll
    for (int g = 0; g < NGROUPS; ++g) {
        s += part[(size_t)g * BATCH + i];
    }
    out[i] = s;
}

// Fallback (round-1 kernel) in case d_ws is too small for partials.
__global__ __launch_bounds__(256) void qw_gather_kernel(
    const int* __restrict__ data,
    const float* __restrict__ table,
    float* __restrict__ out)
{
    const int gtid   = blockIdx.x * blockDim.x + threadIdx.x;
    const int sample = gtid >> 6;
    const int lane   = threadIdx.x & 63;
    if (sample >= BATCH) return;
    const int* __restrict__ row = data + (size_t)sample * N_NEURONS;
    float acc = 0.0f;
#pragma unroll
    for (int k = 0; k < 4; ++k) {
        const int jb = 256 * k + 4 * lane;
        const int4 idx4 = *reinterpret_cast<const int4*>(row + jb);
        acc += table[(size_t)(jb + 0) * TABLE_SIZE + idx4.x];
        acc += table[(size_t)(jb + 1) * TABLE_SIZE + idx4.y];
        acc += table[(size_t)(jb + 2) * TABLE_SIZE + idx4.z];
        acc += table[(size_t)(jb + 3) * TABLE_SIZE + idx4.w];
    }
#pragma unroll
    for (int off = 32; off >= 1; off >>= 1) acc += __shfl_xor(acc, off, 64);
    if (lane == 0) out[sample] = acc;
}

extern "C" void kernel_launch(void* const* d_in, const int* in_sizes, int n_in,
                              void* d_out, int out_size, void* d_ws, size_t ws_size,
                              hipStream_t stream)
{
    const int*   data  = (const int*)d_in[0];    // [BATCH, N_NEURONS] int32
    const float* table = (const float*)d_in[1];  // [N_NEURONS, TABLE_SIZE] float32
    float*       out   = (float*)d_out;          // [BATCH] float32

    const size_t need = (size_t)NGROUPS * BATCH * sizeof(float);  // 256 KB
    if (ws_size >= need) {
        float* part = (float*)d_ws;
        qw_partial_kernel<<<(BATCH / SPB) * NGROUPS, 256, 0, stream>>>(data, table, part);
        qw_reduce_kernel<<<BATCH / 256, 256, 0, stream>>>(part, out);
    } else {
        qw_gather_kernel<<<BATCH / 4, 256, 0, stream>>>(data, table, out);
    }
}